// Round 17
// baseline (125.232 us; speedup 1.0000x reference)
//
#include <hip/hip_runtime.h>
#include <hip/hip_bf16.h>
#include <math.h>

#define Bx 8
#define Cc 256
#define Nn 4096
#define TMPc 512

typedef unsigned short ushort;
typedef unsigned int uint;
typedef unsigned long long ull;
typedef __attribute__((ext_vector_type(8))) short bf16x8;
typedef __attribute__((ext_vector_type(4))) float f32x4;

union F4 { float4 v; float f[4]; };

__device__ __forceinline__ ushort f2bf(float x) {
  uint u = __float_as_uint(x);
  uint r = (u + 0x7fffu + ((u >> 16) & 1u)) >> 16;
  return (ushort)r;
}
// A&S 7.1.26 erf-based GELU, max err ~1.5e-7
__device__ __forceinline__ float gelu_fast(float x) {
  float u = 0.70710678118654752f * x;
  float au = fabsf(u);
  float t = __builtin_amdgcn_rcpf(1.0f + 0.3275911f * au);
  float poly = ((((1.061405429f * t - 1.453152027f) * t + 1.421413741f) * t -
                 0.284496736f) * t + 0.254829592f) * t;
  float e = 1.0f - poly * __expf(-u * u);
  float erfu = copysignf(e, u);
  return 0.5f * x * (1.0f + erfu);
}

typedef const __attribute__((address_space(1))) uint* gp1_t;
typedef __attribute__((address_space(3))) uint* lp3_t;
__device__ __forceinline__ void gload16(void* lds, const void* g) {
  __builtin_amdgcn_global_load_lds((gp1_t)g, (lp3_t)lds, 16, 0, 0);
}
// drain this wave's LDS reads before a DMA overwrites a staging buffer (WAR)
__device__ __forceinline__ void lgkm_fence() {
  asm volatile("s_waitcnt lgkmcnt(0)" ::: "memory");
}
// swizzled ds_read: tiles are [row][32 k] bf16, 64B rows, chunk^=(row&3)
__device__ __forceinline__ bf16x8 fragread(const char* lds, int row, int kc) {
  return *(const bf16x8*)(lds + row * 64 + ((kc ^ (row & 3)) << 4));
}
// wave-private 2KB stage: rows [row0, row0+32) of src (ld ushorts/row),
// k-cols [col, col+32), into buf + w*2048, layout [32 rows][64B] swizzled.
__device__ __forceinline__ void stage2(char* buf, const ushort* src, int ld,
                                       int row0, int col, int w, int prow, int gst) {
  int off = __builtin_amdgcn_readfirstlane(w * 2048);
  gload16(buf + off, src + (size_t)(row0 + prow) * ld + col + gst * 8);
  gload16(buf + off + 1024, src + (size_t)(row0 + 16 + prow) * ld + col + gst * 8);
}

// ==== fused: depthwise 3x3 + transpose + bf16 cvt, weight-convert + zero slice ====
// grid (16, 8, 9): z<8 = conv for batch z; z==8 = weights f32->bf16 + ctxf/sf/cnt zero.
#define CGRP 32
__global__ __launch_bounds__(256) void convw_k(const float* __restrict__ fmap,
                                               const float* __restrict__ Wdw,
                                               ushort* __restrict__ fmapT,
                                               ushort* __restrict__ dwT,
                                               const float* __restrict__ Wq,
                                               const float* __restrict__ Wkv,
                                               const float* __restrict__ Wout,
                                               ushort* __restrict__ WqB,
                                               ushort* __restrict__ WkvB,
                                               ushort* __restrict__ WoutB,
                                               float* __restrict__ ctxf) {
  __shared__ float sin_[CGRP][6 * 64 + 1];
  __shared__ float wl[CGRP][9];
  int t = threadIdx.x;
  if (blockIdx.z == 8) {
    int wid = blockIdx.y * 16 + blockIdx.x;
    // ---- zero ctxf (65536 f4) + sf (1024 f4) + counters (16 f4) = 66576 f4
    for (int i = wid * 256 + t; i < 66576; i += 32768)
      *(float4*)&ctxf[(size_t)i * 4] = (float4){0.f, 0.f, 0.f, 0.f};
    // ---- weight conversion: 128 blocks x 256 threads x 4 groups
#pragma unroll
    for (int g = 0; g < 4; ++g) {
      int i = wid * 1024 + g * 256 + t;
      const float* s;
      ushort* d;
      int idx;
      if (i < 32768) { s = Wq; d = WqB; idx = i; }
      else if (i < 98304) { s = Wkv; d = WkvB; idx = i - 32768; }
      else { s = Wout; d = WoutB; idx = i - 98304; }
      F4 v; v.v = *(const float4*)&s[(size_t)idx * 4];
      union { ushort u[4]; uint2 q; } o;
#pragma unroll
      for (int j = 0; j < 4; ++j) o.u[j] = f2bf(v.f[j]);
      *(uint2*)&d[(size_t)idx * 4] = o.q;
    }
    return;
  }
  int y0 = blockIdx.x * 4;
  int c0 = blockIdx.y * CGRP;
  int z = blockIdx.z;
  for (int i = t; i < CGRP * 9; i += 256) wl[i / 9][i % 9] = Wdw[c0 * 9 + i];
  const float* src = fmap + ((size_t)z * Cc + c0) * 4096;
#pragma unroll
  for (int it = 0; it < 12; ++it) {
    int idx = it * 256 + t;
    int c = idx / 96, rem = idx % 96, yy = rem >> 4, x4 = rem & 15;
    int gy = y0 - 1 + yy;
    F4 v;
    if ((unsigned)gy < 64u)
      v.v = *(const float4*)&src[(size_t)c * 4096 + gy * 64 + x4 * 4];
    else
      v.f[0] = v.f[1] = v.f[2] = v.f[3] = 0.f;
#pragma unroll
    for (int j = 0; j < 4; ++j) sin_[c][yy * 64 + x4 * 4 + j] = v.f[j];
  }
  __syncthreads();
  int c8 = (t & 3) * 8;
  int x = t >> 2;
  size_t nbase = (size_t)z * 4096 + (size_t)y0 * 64;
  union { ushort u[8]; uint4 q; } fo[4], go[4];
#pragma unroll
  for (int cc = 0; cc < 8; ++cc) {
    int c = c8 + cc;
    float wr[9];
#pragma unroll
    for (int k = 0; k < 9; ++k) wr[k] = wl[c][k];
    float r[6][3];
#pragma unroll
    for (int row = 0; row < 6; ++row) {
      r[row][1] = sin_[c][row * 64 + x];
      r[row][0] = (x > 0) ? sin_[c][row * 64 + x - 1] : 0.f;
      r[row][2] = (x < 63) ? sin_[c][row * 64 + x + 1] : 0.f;
    }
#pragma unroll
    for (int it = 0; it < 4; ++it) {
      fo[it].u[cc] = f2bf(r[it + 1][1]);
      float acc = 0.f;
#pragma unroll
      for (int dy = 0; dy < 3; ++dy)
#pragma unroll
        for (int dx = 0; dx < 3; ++dx)
          acc += r[it + dy][dx] * wr[dy * 3 + dx];
      go[it].u[cc] = f2bf(acc);
    }
  }
#pragma unroll
  for (int it = 0; it < 4; ++it) {
    *(uint4*)&fmapT[(nbase + it * 64 + x) * Cc + c0 + c8] = fo[it].q;
    *(uint4*)&dwT[(nbase + it * 64 + x) * Cc + c0 + c8] = go[it].q;
  }
}

// ======== kv GEMM v4: 2-buffer wave-private pipeline, 3 blocks/CU ========
__global__ __launch_bounds__(256, 3) void kvgemm3_k(const ushort* __restrict__ WkvB,
                                                    const ushort* __restrict__ dwT,
                                                    ushort* __restrict__ kv) {
  __shared__ __align__(16) char lds[49152];
  char* Bres = lds;            // 32KB [64 n][512B] swizzled
  char* Asg  = lds + 32768;    // 16KB = 2 x 8KB
  int t = threadIdx.x, w = t >> 6, l = t & 63;
  int z = blockIdx.y, n0 = blockIdx.x * 64;
  int rl = l & 15, kc = l >> 4;
  int prow = l >> 2;
  int gst = (l & 3) ^ ((l >> 2) & 3);

  const ushort* dT = dwT + ((size_t)z * 4096 + n0) * 256;
#pragma unroll
  for (int p = 0; p < 8; ++p) {
    int row = (w * 8 + p) * 2 + (l >> 5);
    int cs = l & 31;
    int off = __builtin_amdgcn_readfirstlane((w * 8 + p) * 1024);
    gload16(Bres + off, dT + (size_t)row * 256 + ((cs ^ (row & 7)) * 8));
  }
  stage2(Asg, WkvB, 256, w * 32, 0, w, prow, gst);  // s=0 into buf 0
  asm volatile("s_waitcnt vmcnt(0)" ::: "memory");
  __syncthreads();  // the only barrier

  ushort* kz = kv + (size_t)z * 1024 * 4096;
#pragma unroll
  for (int c = 0; c < 8; ++c) {
    f32x4 acc[2][4];
#pragma unroll
    for (int i = 0; i < 2; ++i)
#pragma unroll
      for (int j = 0; j < 4; ++j) acc[i][j] = (f32x4){0.f, 0.f, 0.f, 0.f};
#pragma unroll
    for (int k0 = 0; k0 < 8; ++k0) {
      int s = c * 8 + k0;
      if (s + 1 < 64) {
        int s2 = s + 1;
        lgkm_fence();  // WAR: step s-1's fragreads of buf (s+1)&1 must drain
        stage2(Asg + ((s2 & 1) ? 8192 : 0), WkvB, 256, (s2 >> 3) * 128 + w * 32,
               (s2 & 7) * 32, w, prow, gst);
      }
      if (s < 63) asm volatile("s_waitcnt vmcnt(2)" ::: "memory");
      else asm volatile("s_waitcnt vmcnt(0)" ::: "memory");
      const char* bp = Asg + ((s & 1) ? 8192 : 0) + w * 2048;
      bf16x8 a0 = fragread(bp, rl, kc);
      bf16x8 a1 = fragread(bp, 16 + rl, kc);
      __builtin_amdgcn_s_setprio(1);
#pragma unroll
      for (int j = 0; j < 4; ++j) {
        int n = 16 * j + rl;
        bf16x8 b = *(const bf16x8*)(Bres + n * 512 + (((k0 * 4 + kc) ^ (n & 7)) << 4));
        acc[0][j] = __builtin_amdgcn_mfma_f32_16x16x32_bf16(a0, b, acc[0][j], 0, 0, 0);
        acc[1][j] = __builtin_amdgcn_mfma_f32_16x16x32_bf16(a1, b, acc[1][j], 0, 0, 0);
      }
      __builtin_amdgcn_s_setprio(0);
    }
#pragma unroll
    for (int i = 0; i < 2; ++i) {
#pragma unroll
      for (int reg = 0; reg < 4; ++reg) {
        int r = c * 128 + w * 32 + 16 * i + 4 * kc + reg;
#pragma unroll
        for (int j = 0; j < 4; ++j) {
          int col = n0 + 16 * j + rl;
          float v = acc[i][j][reg];
          kz[(size_t)r * 4096 + col] = f2bf(c < 4 ? __expf(v) : v);
        }
      }
    }
  }
}

// ------- ctxT'[e][d] = sum_n v[e][n]*ek[d][n]; s[d] = sum_n ek[d][n] ---------
// 2-phase double-buffer; 8 n-split blocks per page accumulate via atomics;
// the LAST block (completion counter) normalizes the page -> ctxb (bf16).
__global__ __launch_bounds__(256) void ctx_mfma(const ushort* __restrict__ kv,
                                                float* __restrict__ ctxf,
                                                float* __restrict__ sf,
                                                ushort* __restrict__ ctxb,
                                                uint* __restrict__ cnt) {
  __shared__ __align__(16) char lds[16384];  // 2 x (v 4KB | k 4KB)
  __shared__ int lastf;
  int t = threadIdx.x, w = t >> 6, l = t & 63;
  int s = blockIdx.x;
  int h = blockIdx.y & 7, z = blockIdx.y >> 3;
  const ushort* kb = kv + ((size_t)z * 1024 + h * 64) * 4096;
  const ushort* vb = kv + ((size_t)z * 1024 + 512 + h * 64) * 4096;
  f32x4 acc[2][2];
  f32x4 accs[2];
#pragma unroll
  for (int i = 0; i < 2; ++i) {
    accs[i] = (f32x4){0.f, 0.f, 0.f, 0.f};
#pragma unroll
    for (int j = 0; j < 2; ++j) acc[i][j] = (f32x4){0.f, 0.f, 0.f, 0.f};
  }
  bf16x8 ones;
#pragma unroll
  for (int i = 0; i < 8; ++i) ones[i] = (short)0x3F80;
  int wr = (w >> 1) * 32, wc = (w & 1) * 32;
  int rl = l & 15, kc = l >> 4;
  int srow = (l >> 2) & 15, scol = l & 3;
  int row = w * 16 + srow;
  int g = scol ^ (row & 3);
  int soff = __builtin_amdgcn_readfirstlane(w * 1024);
#define CSTG(bb, it)                                                      \
  {                                                                       \
    int k0_ = s * 512 + (it) * 32;                                        \
    gload16(lds + (bb) + soff, vb + (size_t)row * 4096 + k0_ + g * 8);    \
    gload16(lds + (bb) + 4096 + soff, kb + (size_t)row * 4096 + k0_ + g * 8); \
  }
  CSTG(0, 0);
  asm volatile("s_waitcnt vmcnt(0)" ::: "memory");
  __syncthreads();
  for (int it = 0; it < 16; ++it) {
    int cur = (it & 1) << 13;
    if (it + 1 < 16) CSTG(cur ^ 8192, it + 1);  // safe: barrier ended prev iter
    bf16x8 a[2], b[2];
#pragma unroll
    for (int i = 0; i < 2; ++i) a[i] = fragread(lds + cur, wr + i * 16 + rl, kc);
#pragma unroll
    for (int i = 0; i < 2; ++i) b[i] = fragread(lds + cur + 4096, wc + i * 16 + rl, kc);
#pragma unroll
    for (int i = 0; i < 2; ++i)
#pragma unroll
      for (int j = 0; j < 2; ++j)
        acc[i][j] = __builtin_amdgcn_mfma_f32_16x16x32_bf16(a[i], b[j], acc[i][j], 0, 0, 0);
    if (w < 2) {
#pragma unroll
      for (int j = 0; j < 2; ++j)
        accs[j] = __builtin_amdgcn_mfma_f32_16x16x32_bf16(b[j], ones, accs[j], 0, 0, 0);
    }
    asm volatile("s_waitcnt vmcnt(0)" ::: "memory");
    __syncthreads();
  }
  float* cf = ctxf + (size_t)(z * 8 + h) * 4096;
#pragma unroll
  for (int i = 0; i < 2; ++i)
#pragma unroll
    for (int reg = 0; reg < 4; ++reg) {
      int e = wr + i * 16 + kc * 4 + reg;
#pragma unroll
      for (int j = 0; j < 2; ++j) {
        int d = wc + j * 16 + rl;
        atomicAdd(&cf[e * 64 + d], acc[i][j][reg]);
      }
    }
  if (w < 2 && rl == 0) {
    float* sp = sf + (size_t)(z * 8 + h) * 64;
#pragma unroll
    for (int j = 0; j < 2; ++j)
#pragma unroll
      for (int reg = 0; reg < 4; ++reg)
        atomicAdd(&sp[wc + j * 16 + kc * 4 + reg], accs[j][reg]);
  }
#undef CSTG
  // ---- completion counter: last of the 8 n-split blocks normalizes the page
  __syncthreads();  // drains vmcnt: this block's atomics are L2-visible
  if (t == 0) {
    __threadfence();
    uint old = atomicAdd(&cnt[z * 8 + h], 1u);
    lastf = (old == 7u);
  }
  __syncthreads();
  if (lastf) {
    const float* spv = sf + (size_t)(z * 8 + h) * 64;
    ushort* dpg = ctxb + (size_t)(z * 8 + h) * 4096;
    int e = t >> 2, d0 = (t & 3) * 16;
    union { ushort u[16]; uint4 q[2]; } o;
#pragma unroll
    for (int j = 0; j < 16; ++j) {
      int dd = d0 + j;
      float cv = *(volatile const float*)&cf[e * 64 + dd];
      float sv = *(volatile const float*)&spv[dd];
      o.u[j] = f2bf(cv / sv);
    }
    uint4* dp = (uint4*)&dpg[e * 64 + d0];
    dp[0] = o.q[0];
    dp[1] = o.q[1];
  }
}

// ======== MEGA (R14, best measured): q-GEMM->softmax->PV->GELU->out-GEMM ====
__global__ __launch_bounds__(256, 2) void qao_k(const ushort* __restrict__ fmapT,
                                                const ushort* __restrict__ WqB,
                                                const ushort* __restrict__ ctxb,
                                                const ushort* __restrict__ WoutB,
                                                const float* __restrict__ bout,
                                                float* __restrict__ out) {
  __shared__ __align__(16) char lds[73728];
  __shared__ float wsum[4][64];
  char* qbuf = lds;            // 16KB [64 n][256B] XOR (n&7)<<4
  char* Bres = lds + 16384;    // 32KB resident fmapT [64 n][512B] swizzled
  char* Asg  = lds + 49152;    // 24KB = 3 x 8KB staging, wave slice 2KB
  int t = threadIdx.x, w = t >> 6, l = t & 63;
  int z = blockIdx.y, n0 = blockIdx.x * 64;
  int rl = l & 15, kc = l >> 4;
  int prow = l >> 2;
  int gst = (l & 3) ^ ((l >> 2) & 3);
  int hh = w >> 1;
  int wcn = (w & 1) * 32;

  const ushort* fT = fmapT + ((size_t)z * 4096 + n0) * 256;
#pragma unroll
  for (int p = 0; p < 8; ++p) {
    int row = (w * 8 + p) * 2 + (l >> 5);
    int cs = l & 31;
    int off = __builtin_amdgcn_readfirstlane((w * 8 + p) * 1024);
    gload16(Bres + off, fT + (size_t)row * 256 + ((cs ^ (row & 7)) * 8));
  }
  stage2(Asg, WqB, 256, w * 32, 0, w, prow, gst);
  stage2(Asg + 8192, WqB, 256, w * 32, 32, w, prow, gst);

  f32x4 oacc[4][4];  // rows w*64+16i+4kc+reg, cols 16j+rl
#pragma unroll
  for (int i = 0; i < 4; ++i)
#pragma unroll
    for (int j = 0; j < 4; ++j) oacc[i][j] = (f32x4){0.f, 0.f, 0.f, 0.f};

  asm volatile("s_waitcnt vmcnt(0)" ::: "memory");
  __syncthreads();

  for (int c = 0; c < 4; ++c) {
    const ushort* Wqc = WqB + (size_t)(c * 128) * 256;
    // ---- q-GEMM: wave w owns d-rows [w*32, w*32+32), all 64 n. No barriers.
    f32x4 qa[2][4];
#pragma unroll
    for (int i = 0; i < 2; ++i)
#pragma unroll
      for (int j = 0; j < 4; ++j) qa[i][j] = (f32x4){0.f, 0.f, 0.f, 0.f};
#pragma unroll
    for (int k0 = 0; k0 < 8; ++k0) {
      if (k0 + 2 < 8) {
        lgkm_fence();  // WAR: prior iter's fragreads of target buffer
        stage2(Asg + ((k0 + 2) % 3) * 8192, Wqc, 256, w * 32, (k0 + 2) * 32, w, prow, gst);
      }
      if (k0 < 6) asm volatile("s_waitcnt vmcnt(4)" ::: "memory");
      else if (k0 == 6) asm volatile("s_waitcnt vmcnt(2)" ::: "memory");
      else asm volatile("s_waitcnt vmcnt(0)" ::: "memory");
      const char* bp = Asg + (k0 % 3) * 8192 + w * 2048;
      bf16x8 a0 = fragread(bp, rl, kc);
      bf16x8 a1 = fragread(bp, 16 + rl, kc);
      __builtin_amdgcn_s_setprio(1);
#pragma unroll
      for (int j = 0; j < 4; ++j) {
        int n = 16 * j + rl;
        bf16x8 b = *(const bf16x8*)(Bres + n * 512 + (((k0 * 4 + kc) ^ (n & 7)) << 4));
        qa[0][j] = __builtin_amdgcn_mfma_f32_16x16x32_bf16(a0, b, qa[0][j], 0, 0, 0);
        qa[1][j] = __builtin_amdgcn_mfma_f32_16x16x32_bf16(a1, b, qa[1][j], 0, 0, 0);
      }
      __builtin_amdgcn_s_setprio(0);
    }
    // ---- preload ctx fragments direct to registers (this wave's head page)
    const ushort* cpg = ctxb + (size_t)(z * 8 + c * 2 + hh) * 4096;
    bf16x8 ca[2][4];
#pragma unroll
    for (int s2 = 0; s2 < 2; ++s2)
#pragma unroll
      for (int i = 0; i < 4; ++i)
        ca[s2][i] = *(const bf16x8*)(cpg + (size_t)(16 * i + rl) * 64 + s2 * 32 + kc * 8);
    // ---- softmax over d (no max pass; |q| small): wave-pair sum exchange
    float sj[4];
#pragma unroll
    for (int j = 0; j < 4; ++j) {
      float s = 0.f;
#pragma unroll
      for (int i = 0; i < 2; ++i)
#pragma unroll
        for (int reg = 0; reg < 4; ++reg) {
          float e = __expf(qa[i][j][reg]);
          qa[i][j][reg] = e;
          s += e;
        }
      s += __shfl_xor(s, 16, 64);
      s += __shfl_xor(s, 32, 64);
      sj[j] = s;
    }
    if (l < 16) {
#pragma unroll
      for (int j = 0; j < 4; ++j) wsum[w][j * 16 + l] = sj[j];
    }
    __syncthreads();  // (A) wsum exchange; also qbuf WAR vs prev out-GEMM
#pragma unroll
    for (int j = 0; j < 4; ++j) {
      float tot = wsum[w][16 * j + rl] + wsum[w ^ 1][16 * j + rl];
      float inv = 0.125f / tot;
#pragma unroll
      for (int i = 0; i < 2; ++i)
#pragma unroll
        for (int reg = 0; reg < 4; ++reg) qa[i][j][reg] *= inv;
    }
    // ---- write q to qbuf [n][d] (b64 packed, swizzled)
#pragma unroll
    for (int i = 0; i < 2; ++i)
#pragma unroll
      for (int j = 0; j < 4; ++j) {
        int n = 16 * j + rl;
        int dby = (w * 32 + 16 * i + 4 * kc) * 2;
        union { ushort u[4]; ull q; } pk;
#pragma unroll
        for (int reg = 0; reg < 4; ++reg) pk.u[reg] = f2bf(qa[i][j][reg]);
        *(ull*)(qbuf + n * 256 + (dby ^ ((n & 7) << 4))) = pk.q;
      }
    __syncthreads();  // (B) qbuf visible
    // ---- PV: head hh, e rows 0..63, n cols wcn..wcn+31, K=64
    f32x4 pacc[4][2];
#pragma unroll
    for (int i = 0; i < 4; ++i)
#pragma unroll
      for (int j = 0; j < 2; ++j) pacc[i][j] = (f32x4){0.f, 0.f, 0.f, 0.f};
    __builtin_amdgcn_s_setprio(1);
#pragma unroll
    for (int s2 = 0; s2 < 2; ++s2) {
      bf16x8 pb[2];
#pragma unroll
      for (int j = 0; j < 2; ++j) {
        int n = wcn + 16 * j + rl;
        int dby = hh * 128 + s2 * 64 + kc * 16;
        pb[j] = *(const bf16x8*)(qbuf + n * 256 + (dby ^ ((n & 7) << 4)));
      }
#pragma unroll
      for (int i = 0; i < 4; ++i)
#pragma unroll
        for (int j = 0; j < 2; ++j)
          pacc[i][j] = __builtin_amdgcn_mfma_f32_16x16x32_bf16(ca[s2][i], pb[j], pacc[i][j], 0, 0, 0);
    }
    __builtin_amdgcn_s_setprio(0);
    // ---- GELU -> gout into qbuf (wave-private n rows; no barrier needed)
#pragma unroll
    for (int i = 0; i < 4; ++i)
#pragma unroll
      for (int j = 0; j < 2; ++j) {
        int n = wcn + 16 * j + rl;
        int mby = (hh * 64 + 16 * i + 4 * kc) * 2;
        union { ushort u[4]; ull q; } pk;
#pragma unroll
        for (int reg = 0; reg < 4; ++reg) pk.u[reg] = f2bf(gelu_fast(pacc[i][j][reg]));
        *(ull*)(qbuf + n * 256 + (mby ^ ((n & 7) << 4))) = pk.q;
      }
    __syncthreads();  // (C) gout visible; drains lgkm before staging below
    // ---- out-GEMM: 8 half-steps, wave-private Wout staging, no barriers
    stage2(Asg, WoutB, 512, w * 64, c * 128, w, prow, gst);             // s=0
    stage2(Asg + 8192, WoutB, 512, w * 64 + 32, c * 128, w, prow, gst); // s=1
    bf16x8 ob[4];
#pragma unroll
    for (int s = 0; s < 8; ++s) {
      if (s + 2 < 8) {
        int s2 = s + 2;
        lgkm_fence();  // WAR: prior iter's fragreads of target buffer
        stage2(Asg + (s2 % 3) * 8192, WoutB, 512, w * 64 + (s2 & 1) * 32,
               c * 128 + (s2 >> 1) * 32, w, prow, gst);
      }
      if (s < 6) asm volatile("s_waitcnt vmcnt(4)" ::: "memory");
      else if (s == 6) asm volatile("s_waitcnt vmcnt(2)" ::: "memory");
      else asm volatile("s_waitcnt vmcnt(0)" ::: "memory");
      int half = s & 1, ks = s >> 1;
      if (half == 0) {
#pragma unroll
        for (int j = 0; j < 4; ++j) {
          int n = 16 * j + rl;
          ob[j] = *(const bf16x8*)(qbuf + n * 256 + ((ks * 64 + kc * 16) ^ ((n & 7) << 4)));
        }
      }
      const char* bp = Asg + (s % 3) * 8192 + w * 2048;
      bf16x8 a0 = fragread(bp, rl, kc);
      bf16x8 a1 = fragread(bp, 16 + rl, kc);
      __builtin_amdgcn_s_setprio(1);
#pragma unroll
      for (int j = 0; j < 4; ++j) {
        oacc[half * 2][j] = __builtin_amdgcn_mfma_f32_16x16x32_bf16(a0, ob[j], oacc[half * 2][j], 0, 0, 0);
        oacc[half * 2 + 1][j] = __builtin_amdgcn_mfma_f32_16x16x32_bf16(a1, ob[j], oacc[half * 2 + 1][j], 0, 0, 0);
      }
      __builtin_amdgcn_s_setprio(0);
    }
    // pre-issue next chunk's q stages (overwrites bufs 0,1 read at s=6,7)
    if (c < 3) {
      const ushort* Wqn = WqB + (size_t)((c + 1) * 128) * 256;
      lgkm_fence();  // WAR: s=6/7 fragreads of bufs 0,1 must drain first
      stage2(Asg, Wqn, 256, w * 32, 0, w, prow, gst);
      stage2(Asg + 8192, Wqn, 256, w * 32, 32, w, prow, gst);
    }
  }
  // ---- epilogue: bias + f32 store
  float* oz = out + (size_t)z * Cc * Nn + n0;
#pragma unroll
  for (int i = 0; i < 4; ++i) {
#pragma unroll
    for (int reg = 0; reg < 4; ++reg) {
      int crow = w * 64 + 16 * i + 4 * kc + reg;
      float bv = bout[crow];
      float* rowp = oz + (size_t)crow * 4096;
#pragma unroll
      for (int j = 0; j < 4; ++j) rowp[16 * j + rl] = oacc[i][j][reg] + bv;
    }
  }
}

extern "C" void kernel_launch(void* const* d_in, const int* in_sizes, int n_in,
                              void* d_out, int out_size, void* d_ws, size_t ws_size,
                              hipStream_t stream) {
  (void)in_sizes; (void)n_in; (void)out_size; (void)ws_size;
  const float* fmap = (const float*)d_in[0];
  const float* Wq   = (const float*)d_in[1];
  const float* Wdw  = (const float*)d_in[2];
  const float* Wkv  = (const float*)d_in[3];
  const float* Wout = (const float*)d_in[4];
  const float* bout = (const float*)d_in[5];
  float* out = (float*)d_out;

  ushort* WqB   = (ushort*)d_ws;
  ushort* WkvB  = WqB + 512 * 256;
  ushort* WoutB = WkvB + 1024 * 256;
  ushort* fmapT = WoutB + 256 * 512;
  ushort* dwT   = fmapT + (size_t)Bx * 4096 * 256;
  ushort* kv    = dwT + (size_t)Bx * 4096 * 256;
  ushort* ctxb  = kv + (size_t)Bx * 1024 * 4096;
  float*  ctxf  = (float*)(ctxb + (size_t)Bx * 8 * 4096);
  float*  sf    = ctxf + (size_t)Bx * 8 * 64 * 64;
  uint*   cnt   = (uint*)(sf + (size_t)Bx * 8 * 64);

  convw_k<<<dim3(16, 8, 9), 256, 0, stream>>>(fmap, Wdw, fmapT, dwT,
                                              Wq, Wkv, Wout, WqB, WkvB, WoutB, ctxf);
  kvgemm3_k<<<dim3(64, Bx), 256, 0, stream>>>(WkvB, dwT, kv);
  ctx_mfma<<<dim3(8, Bx * 8), 256, 0, stream>>>(kv, ctxf, sf, ctxb, cnt);
  qao_k<<<dim3(64, Bx), 256, 0, stream>>>(fmapT, WqB, ctxb, WoutB, bout, out);
}

// Round 18
// 114.390 us; speedup vs baseline: 1.0948x; 1.0948x over previous
//
#include <hip/hip_runtime.h>
#include <hip/hip_bf16.h>
#include <math.h>

#define Bx 8
#define Cc 256
#define Nn 4096
#define TMPc 512

typedef unsigned short ushort;
typedef unsigned int uint;
typedef unsigned long long ull;
typedef __attribute__((ext_vector_type(8))) short bf16x8;
typedef __attribute__((ext_vector_type(4))) float f32x4;

union F4 { float4 v; float f[4]; };

__device__ __forceinline__ ushort f2bf(float x) {
  uint u = __float_as_uint(x);
  uint r = (u + 0x7fffu + ((u >> 16) & 1u)) >> 16;
  return (ushort)r;
}
// A&S 7.1.26 erf-based GELU, max err ~1.5e-7
__device__ __forceinline__ float gelu_fast(float x) {
  float u = 0.70710678118654752f * x;
  float au = fabsf(u);
  float t = __builtin_amdgcn_rcpf(1.0f + 0.3275911f * au);
  float poly = ((((1.061405429f * t - 1.453152027f) * t + 1.421413741f) * t -
                 0.284496736f) * t + 0.254829592f) * t;
  float e = 1.0f - poly * __expf(-u * u);
  float erfu = copysignf(e, u);
  return 0.5f * x * (1.0f + erfu);
}

typedef const __attribute__((address_space(1))) uint* gp1_t;
typedef __attribute__((address_space(3))) uint* lp3_t;
__device__ __forceinline__ void gload16(void* lds, const void* g) {
  __builtin_amdgcn_global_load_lds((gp1_t)g, (lp3_t)lds, 16, 0, 0);
}
// drain this wave's LDS reads before a DMA overwrites a staging buffer (WAR)
__device__ __forceinline__ void lgkm_fence() {
  asm volatile("s_waitcnt lgkmcnt(0)" ::: "memory");
}
// swizzled ds_read: tiles are [row][32 k] bf16, 64B rows, chunk^=(row&3)
__device__ __forceinline__ bf16x8 fragread(const char* lds, int row, int kc) {
  return *(const bf16x8*)(lds + row * 64 + ((kc ^ (row & 3)) << 4));
}
// wave-private 2KB stage: rows [row0, row0+32) of src (ld ushorts/row),
// k-cols [col, col+32), into buf + w*2048, layout [32 rows][64B] swizzled.
__device__ __forceinline__ void stage2(char* buf, const ushort* src, int ld,
                                       int row0, int col, int w, int prow, int gst) {
  int off = __builtin_amdgcn_readfirstlane(w * 2048);
  gload16(buf + off, src + (size_t)(row0 + prow) * ld + col + gst * 8);
  gload16(buf + off + 1024, src + (size_t)(row0 + 16 + prow) * ld + col + gst * 8);
}

// ==== fused: depthwise 3x3 + transpose + bf16 cvt, weight-convert + zero slice ====
// grid (16, 8, 9): z<8 = conv for batch z; z==8 = weights f32->bf16 + ctxf zero.
#define CGRP 32
__global__ __launch_bounds__(256) void convw_k(const float* __restrict__ fmap,
                                               const float* __restrict__ Wdw,
                                               ushort* __restrict__ fmapT,
                                               ushort* __restrict__ dwT,
                                               const float* __restrict__ Wq,
                                               const float* __restrict__ Wkv,
                                               const float* __restrict__ Wout,
                                               ushort* __restrict__ WqB,
                                               ushort* __restrict__ WkvB,
                                               ushort* __restrict__ WoutB,
                                               float* __restrict__ ctxf) {
  __shared__ float sin_[CGRP][6 * 64 + 1];
  __shared__ float wl[CGRP][9];
  int t = threadIdx.x;
  if (blockIdx.z == 8) {
    int wid = blockIdx.y * 16 + blockIdx.x;
    // ---- zero ctxf+sf (contiguous 66560 float4)
    for (int i = wid * 256 + t; i < 66560; i += 32768)
      *(float4*)&ctxf[(size_t)i * 4] = (float4){0.f, 0.f, 0.f, 0.f};
    // ---- weight conversion: 128 blocks x 256 threads x 4 groups
#pragma unroll
    for (int g = 0; g < 4; ++g) {
      int i = wid * 1024 + g * 256 + t;
      const float* s;
      ushort* d;
      int idx;
      if (i < 32768) { s = Wq; d = WqB; idx = i; }
      else if (i < 98304) { s = Wkv; d = WkvB; idx = i - 32768; }
      else { s = Wout; d = WoutB; idx = i - 98304; }
      F4 v; v.v = *(const float4*)&s[(size_t)idx * 4];
      union { ushort u[4]; uint2 q; } o;
#pragma unroll
      for (int j = 0; j < 4; ++j) o.u[j] = f2bf(v.f[j]);
      *(uint2*)&d[(size_t)idx * 4] = o.q;
    }
    return;
  }
  int y0 = blockIdx.x * 4;
  int c0 = blockIdx.y * CGRP;
  int z = blockIdx.z;
  for (int i = t; i < CGRP * 9; i += 256) wl[i / 9][i % 9] = Wdw[c0 * 9 + i];
  const float* src = fmap + ((size_t)z * Cc + c0) * 4096;
#pragma unroll
  for (int it = 0; it < 12; ++it) {
    int idx = it * 256 + t;
    int c = idx / 96, rem = idx % 96, yy = rem >> 4, x4 = rem & 15;
    int gy = y0 - 1 + yy;
    F4 v;
    if ((unsigned)gy < 64u)
      v.v = *(const float4*)&src[(size_t)c * 4096 + gy * 64 + x4 * 4];
    else
      v.f[0] = v.f[1] = v.f[2] = v.f[3] = 0.f;
#pragma unroll
    for (int j = 0; j < 4; ++j) sin_[c][yy * 64 + x4 * 4 + j] = v.f[j];
  }
  __syncthreads();
  int c8 = (t & 3) * 8;
  int x = t >> 2;
  size_t nbase = (size_t)z * 4096 + (size_t)y0 * 64;
  union { ushort u[8]; uint4 q; } fo[4], go[4];
#pragma unroll
  for (int cc = 0; cc < 8; ++cc) {
    int c = c8 + cc;
    float wr[9];
#pragma unroll
    for (int k = 0; k < 9; ++k) wr[k] = wl[c][k];
    float r[6][3];
#pragma unroll
    for (int row = 0; row < 6; ++row) {
      r[row][1] = sin_[c][row * 64 + x];
      r[row][0] = (x > 0) ? sin_[c][row * 64 + x - 1] : 0.f;
      r[row][2] = (x < 63) ? sin_[c][row * 64 + x + 1] : 0.f;
    }
#pragma unroll
    for (int it = 0; it < 4; ++it) {
      fo[it].u[cc] = f2bf(r[it + 1][1]);
      float acc = 0.f;
#pragma unroll
      for (int dy = 0; dy < 3; ++dy)
#pragma unroll
        for (int dx = 0; dx < 3; ++dx)
          acc += r[it + dy][dx] * wr[dy * 3 + dx];
      go[it].u[cc] = f2bf(acc);
    }
  }
#pragma unroll
  for (int it = 0; it < 4; ++it) {
    *(uint4*)&fmapT[(nbase + it * 64 + x) * Cc + c0 + c8] = fo[it].q;
    *(uint4*)&dwT[(nbase + it * 64 + x) * Cc + c0 + c8] = go[it].q;
  }
}

// ======== kv GEMM v4: 2-buffer wave-private pipeline, 3 blocks/CU ========
__global__ __launch_bounds__(256, 3) void kvgemm3_k(const ushort* __restrict__ WkvB,
                                                    const ushort* __restrict__ dwT,
                                                    ushort* __restrict__ kv) {
  __shared__ __align__(16) char lds[49152];
  char* Bres = lds;            // 32KB [64 n][512B] swizzled
  char* Asg  = lds + 32768;    // 16KB = 2 x 8KB
  int t = threadIdx.x, w = t >> 6, l = t & 63;
  int z = blockIdx.y, n0 = blockIdx.x * 64;
  int rl = l & 15, kc = l >> 4;
  int prow = l >> 2;
  int gst = (l & 3) ^ ((l >> 2) & 3);

  const ushort* dT = dwT + ((size_t)z * 4096 + n0) * 256;
#pragma unroll
  for (int p = 0; p < 8; ++p) {
    int row = (w * 8 + p) * 2 + (l >> 5);
    int cs = l & 31;
    int off = __builtin_amdgcn_readfirstlane((w * 8 + p) * 1024);
    gload16(Bres + off, dT + (size_t)row * 256 + ((cs ^ (row & 7)) * 8));
  }
  stage2(Asg, WkvB, 256, w * 32, 0, w, prow, gst);  // s=0 into buf 0
  asm volatile("s_waitcnt vmcnt(0)" ::: "memory");
  __syncthreads();  // the only barrier

  ushort* kz = kv + (size_t)z * 1024 * 4096;
#pragma unroll
  for (int c = 0; c < 8; ++c) {
    f32x4 acc[2][4];
#pragma unroll
    for (int i = 0; i < 2; ++i)
#pragma unroll
      for (int j = 0; j < 4; ++j) acc[i][j] = (f32x4){0.f, 0.f, 0.f, 0.f};
#pragma unroll
    for (int k0 = 0; k0 < 8; ++k0) {
      int s = c * 8 + k0;
      if (s + 1 < 64) {
        int s2 = s + 1;
        lgkm_fence();  // WAR: step s-1's fragreads of buf (s+1)&1 must drain
        stage2(Asg + ((s2 & 1) ? 8192 : 0), WkvB, 256, (s2 >> 3) * 128 + w * 32,
               (s2 & 7) * 32, w, prow, gst);
      }
      if (s < 63) asm volatile("s_waitcnt vmcnt(2)" ::: "memory");
      else asm volatile("s_waitcnt vmcnt(0)" ::: "memory");
      const char* bp = Asg + ((s & 1) ? 8192 : 0) + w * 2048;
      bf16x8 a0 = fragread(bp, rl, kc);
      bf16x8 a1 = fragread(bp, 16 + rl, kc);
      __builtin_amdgcn_s_setprio(1);
#pragma unroll
      for (int j = 0; j < 4; ++j) {
        int n = 16 * j + rl;
        bf16x8 b = *(const bf16x8*)(Bres + n * 512 + (((k0 * 4 + kc) ^ (n & 7)) << 4));
        acc[0][j] = __builtin_amdgcn_mfma_f32_16x16x32_bf16(a0, b, acc[0][j], 0, 0, 0);
        acc[1][j] = __builtin_amdgcn_mfma_f32_16x16x32_bf16(a1, b, acc[1][j], 0, 0, 0);
      }
      __builtin_amdgcn_s_setprio(0);
    }
#pragma unroll
    for (int i = 0; i < 2; ++i) {
#pragma unroll
      for (int reg = 0; reg < 4; ++reg) {
        int r = c * 128 + w * 32 + 16 * i + 4 * kc + reg;
#pragma unroll
        for (int j = 0; j < 4; ++j) {
          int col = n0 + 16 * j + rl;
          float v = acc[i][j][reg];
          kz[(size_t)r * 4096 + col] = f2bf(c < 4 ? __expf(v) : v);
        }
      }
    }
  }
}

// ------- ctxT'[e][d] = sum_n v[e][n]*ek[d][n]; also s[d] = sum_n ek[d][n] -------
// 2-phase double-buffer (R13). grid (8 n-splits, 64 pages).
__global__ __launch_bounds__(256) void ctx_mfma(const ushort* __restrict__ kv,
                                                float* __restrict__ ctxf,
                                                float* __restrict__ sf) {
  __shared__ __align__(16) char lds[16384];  // 2 x (v 4KB | k 4KB)
  int t = threadIdx.x, w = t >> 6, l = t & 63;
  int s = blockIdx.x;
  int h = blockIdx.y & 7, z = blockIdx.y >> 3;
  const ushort* kb = kv + ((size_t)z * 1024 + h * 64) * 4096;
  const ushort* vb = kv + ((size_t)z * 1024 + 512 + h * 64) * 4096;
  f32x4 acc[2][2];
  f32x4 accs[2];
#pragma unroll
  for (int i = 0; i < 2; ++i) {
    accs[i] = (f32x4){0.f, 0.f, 0.f, 0.f};
#pragma unroll
    for (int j = 0; j < 2; ++j) acc[i][j] = (f32x4){0.f, 0.f, 0.f, 0.f};
  }
  bf16x8 ones;
#pragma unroll
  for (int i = 0; i < 8; ++i) ones[i] = (short)0x3F80;
  int wr = (w >> 1) * 32, wc = (w & 1) * 32;
  int rl = l & 15, kc = l >> 4;
  int srow = (l >> 2) & 15, scol = l & 3;
  int row = w * 16 + srow;
  int g = scol ^ (row & 3);
  int soff = __builtin_amdgcn_readfirstlane(w * 1024);
#define CSTG(bb, it)                                                      \
  {                                                                       \
    int k0_ = s * 512 + (it) * 32;                                        \
    gload16(lds + (bb) + soff, vb + (size_t)row * 4096 + k0_ + g * 8);    \
    gload16(lds + (bb) + 4096 + soff, kb + (size_t)row * 4096 + k0_ + g * 8); \
  }
  CSTG(0, 0);
  asm volatile("s_waitcnt vmcnt(0)" ::: "memory");
  __syncthreads();
  for (int it = 0; it < 16; ++it) {
    int cur = (it & 1) << 13;
    if (it + 1 < 16) CSTG(cur ^ 8192, it + 1);  // safe: barrier ended prev iter
    bf16x8 a[2], b[2];
#pragma unroll
    for (int i = 0; i < 2; ++i) a[i] = fragread(lds + cur, wr + i * 16 + rl, kc);
#pragma unroll
    for (int i = 0; i < 2; ++i) b[i] = fragread(lds + cur + 4096, wc + i * 16 + rl, kc);
#pragma unroll
    for (int i = 0; i < 2; ++i)
#pragma unroll
      for (int j = 0; j < 2; ++j)
        acc[i][j] = __builtin_amdgcn_mfma_f32_16x16x32_bf16(a[i], b[j], acc[i][j], 0, 0, 0);
    if (w < 2) {
#pragma unroll
      for (int j = 0; j < 2; ++j)
        accs[j] = __builtin_amdgcn_mfma_f32_16x16x32_bf16(b[j], ones, accs[j], 0, 0, 0);
    }
    asm volatile("s_waitcnt vmcnt(0)" ::: "memory");
    __syncthreads();
  }
  float* cf = ctxf + (size_t)(z * 8 + h) * 4096;
#pragma unroll
  for (int i = 0; i < 2; ++i)
#pragma unroll
    for (int reg = 0; reg < 4; ++reg) {
      int e = wr + i * 16 + kc * 4 + reg;
#pragma unroll
      for (int j = 0; j < 2; ++j) {
        int d = wc + j * 16 + rl;
        atomicAdd(&cf[e * 64 + d], acc[i][j][reg]);
      }
    }
  if (w < 2 && rl == 0) {
    float* sp = sf + (size_t)(z * 8 + h) * 64;
#pragma unroll
    for (int j = 0; j < 2; ++j)
#pragma unroll
      for (int reg = 0; reg < 4; ++reg)
        atomicAdd(&sp[wc + j * 16 + kc * 4 + reg], accs[j][reg]);
  }
#undef CSTG
}

// ------------- ctx normalize (1/s_d) + f32 -> linear bf16 pages -------------
__global__ __launch_bounds__(256) void ctx_cvt(const float* __restrict__ ctxf,
                                               const float* __restrict__ sf,
                                               ushort* __restrict__ ctxb) {
  int page = blockIdx.x;
  const float* s = ctxf + (size_t)page * 4096;
  const float* sp = sf + (size_t)page * 64;
  ushort* d = ctxb + (size_t)page * 4096;
  int t = threadIdx.x;
  int e = t >> 2, d0 = (t & 3) * 16;
  union { ushort u[16]; uint4 q[2]; } o;
#pragma unroll
  for (int j = 0; j < 16; ++j) {
    int dd = d0 + j;
    o.u[j] = f2bf(s[e * 64 + dd] / sp[dd]);
  }
  uint4* dp = (uint4*)&d[e * 64 + d0];
  dp[0] = o.q[0]; dp[1] = o.q[1];
}

// ======== MEGA (R14, best measured): q-GEMM->softmax->PV->GELU->out-GEMM ====
__global__ __launch_bounds__(256, 2) void qao_k(const ushort* __restrict__ fmapT,
                                                const ushort* __restrict__ WqB,
                                                const ushort* __restrict__ ctxb,
                                                const ushort* __restrict__ WoutB,
                                                const float* __restrict__ bout,
                                                float* __restrict__ out) {
  __shared__ __align__(16) char lds[73728];
  __shared__ float wsum[4][64];
  char* qbuf = lds;            // 16KB [64 n][256B] XOR (n&7)<<4
  char* Bres = lds + 16384;    // 32KB resident fmapT [64 n][512B] swizzled
  char* Asg  = lds + 49152;    // 24KB = 3 x 8KB staging, wave slice 2KB
  int t = threadIdx.x, w = t >> 6, l = t & 63;
  int z = blockIdx.y, n0 = blockIdx.x * 64;
  int rl = l & 15, kc = l >> 4;
  int prow = l >> 2;
  int gst = (l & 3) ^ ((l >> 2) & 3);
  int hh = w >> 1;
  int wcn = (w & 1) * 32;

  const ushort* fT = fmapT + ((size_t)z * 4096 + n0) * 256;
#pragma unroll
  for (int p = 0; p < 8; ++p) {
    int row = (w * 8 + p) * 2 + (l >> 5);
    int cs = l & 31;
    int off = __builtin_amdgcn_readfirstlane((w * 8 + p) * 1024);
    gload16(Bres + off, fT + (size_t)row * 256 + ((cs ^ (row & 7)) * 8));
  }
  stage2(Asg, WqB, 256, w * 32, 0, w, prow, gst);
  stage2(Asg + 8192, WqB, 256, w * 32, 32, w, prow, gst);

  f32x4 oacc[4][4];  // rows w*64+16i+4kc+reg, cols 16j+rl
#pragma unroll
  for (int i = 0; i < 4; ++i)
#pragma unroll
    for (int j = 0; j < 4; ++j) oacc[i][j] = (f32x4){0.f, 0.f, 0.f, 0.f};

  asm volatile("s_waitcnt vmcnt(0)" ::: "memory");
  __syncthreads();

  for (int c = 0; c < 4; ++c) {
    const ushort* Wqc = WqB + (size_t)(c * 128) * 256;
    // ---- q-GEMM: wave w owns d-rows [w*32, w*32+32), all 64 n. No barriers.
    f32x4 qa[2][4];
#pragma unroll
    for (int i = 0; i < 2; ++i)
#pragma unroll
      for (int j = 0; j < 4; ++j) qa[i][j] = (f32x4){0.f, 0.f, 0.f, 0.f};
#pragma unroll
    for (int k0 = 0; k0 < 8; ++k0) {
      if (k0 + 2 < 8) {
        lgkm_fence();  // WAR: prior iter's fragreads of target buffer
        stage2(Asg + ((k0 + 2) % 3) * 8192, Wqc, 256, w * 32, (k0 + 2) * 32, w, prow, gst);
      }
      if (k0 < 6) asm volatile("s_waitcnt vmcnt(4)" ::: "memory");
      else if (k0 == 6) asm volatile("s_waitcnt vmcnt(2)" ::: "memory");
      else asm volatile("s_waitcnt vmcnt(0)" ::: "memory");
      const char* bp = Asg + (k0 % 3) * 8192 + w * 2048;
      bf16x8 a0 = fragread(bp, rl, kc);
      bf16x8 a1 = fragread(bp, 16 + rl, kc);
      __builtin_amdgcn_s_setprio(1);
#pragma unroll
      for (int j = 0; j < 4; ++j) {
        int n = 16 * j + rl;
        bf16x8 b = *(const bf16x8*)(Bres + n * 512 + (((k0 * 4 + kc) ^ (n & 7)) << 4));
        qa[0][j] = __builtin_amdgcn_mfma_f32_16x16x32_bf16(a0, b, qa[0][j], 0, 0, 0);
        qa[1][j] = __builtin_amdgcn_mfma_f32_16x16x32_bf16(a1, b, qa[1][j], 0, 0, 0);
      }
      __builtin_amdgcn_s_setprio(0);
    }
    // ---- preload ctx fragments direct to registers (this wave's head page)
    const ushort* cpg = ctxb + (size_t)(z * 8 + c * 2 + hh) * 4096;
    bf16x8 ca[2][4];
#pragma unroll
    for (int s2 = 0; s2 < 2; ++s2)
#pragma unroll
      for (int i = 0; i < 4; ++i)
        ca[s2][i] = *(const bf16x8*)(cpg + (size_t)(16 * i + rl) * 64 + s2 * 32 + kc * 8);
    // ---- softmax over d (no max pass; |q| small): wave-pair sum exchange
    float sj[4];
#pragma unroll
    for (int j = 0; j < 4; ++j) {
      float s = 0.f;
#pragma unroll
      for (int i = 0; i < 2; ++i)
#pragma unroll
        for (int reg = 0; reg < 4; ++reg) {
          float e = __expf(qa[i][j][reg]);
          qa[i][j][reg] = e;
          s += e;
        }
      s += __shfl_xor(s, 16, 64);
      s += __shfl_xor(s, 32, 64);
      sj[j] = s;
    }
    if (l < 16) {
#pragma unroll
      for (int j = 0; j < 4; ++j) wsum[w][j * 16 + l] = sj[j];
    }
    __syncthreads();  // (A) wsum exchange; also qbuf WAR vs prev out-GEMM
#pragma unroll
    for (int j = 0; j < 4; ++j) {
      float tot = wsum[w][16 * j + rl] + wsum[w ^ 1][16 * j + rl];
      float inv = 0.125f / tot;
#pragma unroll
      for (int i = 0; i < 2; ++i)
#pragma unroll
        for (int reg = 0; reg < 4; ++reg) qa[i][j][reg] *= inv;
    }
    // ---- write q to qbuf [n][d] (b64 packed, swizzled)
#pragma unroll
    for (int i = 0; i < 2; ++i)
#pragma unroll
      for (int j = 0; j < 4; ++j) {
        int n = 16 * j + rl;
        int dby = (w * 32 + 16 * i + 4 * kc) * 2;
        union { ushort u[4]; ull q; } pk;
#pragma unroll
        for (int reg = 0; reg < 4; ++reg) pk.u[reg] = f2bf(qa[i][j][reg]);
        *(ull*)(qbuf + n * 256 + (dby ^ ((n & 7) << 4))) = pk.q;
      }
    __syncthreads();  // (B) qbuf visible
    // ---- PV: head hh, e rows 0..63, n cols wcn..wcn+31, K=64
    f32x4 pacc[4][2];
#pragma unroll
    for (int i = 0; i < 4; ++i)
#pragma unroll
      for (int j = 0; j < 2; ++j) pacc[i][j] = (f32x4){0.f, 0.f, 0.f, 0.f};
    __builtin_amdgcn_s_setprio(1);
#pragma unroll
    for (int s2 = 0; s2 < 2; ++s2) {
      bf16x8 pb[2];
#pragma unroll
      for (int j = 0; j < 2; ++j) {
        int n = wcn + 16 * j + rl;
        int dby = hh * 128 + s2 * 64 + kc * 16;
        pb[j] = *(const bf16x8*)(qbuf + n * 256 + (dby ^ ((n & 7) << 4)));
      }
#pragma unroll
      for (int i = 0; i < 4; ++i)
#pragma unroll
        for (int j = 0; j < 2; ++j)
          pacc[i][j] = __builtin_amdgcn_mfma_f32_16x16x32_bf16(ca[s2][i], pb[j], pacc[i][j], 0, 0, 0);
    }
    __builtin_amdgcn_s_setprio(0);
    // ---- GELU -> gout into qbuf (wave-private n rows; no barrier needed)
#pragma unroll
    for (int i = 0; i < 4; ++i)
#pragma unroll
      for (int j = 0; j < 2; ++j) {
        int n = wcn + 16 * j + rl;
        int mby = (hh * 64 + 16 * i + 4 * kc) * 2;
        union { ushort u[4]; ull q; } pk;
#pragma unroll
        for (int reg = 0; reg < 4; ++reg) pk.u[reg] = f2bf(gelu_fast(pacc[i][j][reg]));
        *(ull*)(qbuf + n * 256 + (mby ^ ((n & 7) << 4))) = pk.q;
      }
    __syncthreads();  // (C) gout visible; drains lgkm before staging below
    // ---- out-GEMM: 8 half-steps, wave-private Wout staging, no barriers
    stage2(Asg, WoutB, 512, w * 64, c * 128, w, prow, gst);             // s=0
    stage2(Asg + 8192, WoutB, 512, w * 64 + 32, c * 128, w, prow, gst); // s=1
    bf16x8 ob[4];
#pragma unroll
    for (int s = 0; s < 8; ++s) {
      if (s + 2 < 8) {
        int s2 = s + 2;
        lgkm_fence();  // WAR: prior iter's fragreads of target buffer
        stage2(Asg + (s2 % 3) * 8192, WoutB, 512, w * 64 + (s2 & 1) * 32,
               c * 128 + (s2 >> 1) * 32, w, prow, gst);
      }
      if (s < 6) asm volatile("s_waitcnt vmcnt(4)" ::: "memory");
      else if (s == 6) asm volatile("s_waitcnt vmcnt(2)" ::: "memory");
      else asm volatile("s_waitcnt vmcnt(0)" ::: "memory");
      int half = s & 1, ks = s >> 1;
      if (half == 0) {
#pragma unroll
        for (int j = 0; j < 4; ++j) {
          int n = 16 * j + rl;
          ob[j] = *(const bf16x8*)(qbuf + n * 256 + ((ks * 64 + kc * 16) ^ ((n & 7) << 4)));
        }
      }
      const char* bp = Asg + (s % 3) * 8192 + w * 2048;
      bf16x8 a0 = fragread(bp, rl, kc);
      bf16x8 a1 = fragread(bp, 16 + rl, kc);
      __builtin_amdgcn_s_setprio(1);
#pragma unroll
      for (int j = 0; j < 4; ++j) {
        oacc[half * 2][j] = __builtin_amdgcn_mfma_f32_16x16x32_bf16(a0, ob[j], oacc[half * 2][j], 0, 0, 0);
        oacc[half * 2 + 1][j] = __builtin_amdgcn_mfma_f32_16x16x32_bf16(a1, ob[j], oacc[half * 2 + 1][j], 0, 0, 0);
      }
      __builtin_amdgcn_s_setprio(0);
    }
    // pre-issue next chunk's q stages (overwrites bufs 0,1 read at s=6,7)
    if (c < 3) {
      const ushort* Wqn = WqB + (size_t)((c + 1) * 128) * 256;
      lgkm_fence();  // WAR: s=6/7 fragreads of bufs 0,1 must drain first
      stage2(Asg, Wqn, 256, w * 32, 0, w, prow, gst);
      stage2(Asg + 8192, Wqn, 256, w * 32, 32, w, prow, gst);
    }
  }
  // ---- epilogue: bias + f32 store
  float* oz = out + (size_t)z * Cc * Nn + n0;
#pragma unroll
  for (int i = 0; i < 4; ++i) {
#pragma unroll
    for (int reg = 0; reg < 4; ++reg) {
      int crow = w * 64 + 16 * i + 4 * kc + reg;
      float bv = bout[crow];
      float* rowp = oz + (size_t)crow * 4096;
#pragma unroll
      for (int j = 0; j < 4; ++j) rowp[16 * j + rl] = oacc[i][j][reg] + bv;
    }
  }
}

extern "C" void kernel_launch(void* const* d_in, const int* in_sizes, int n_in,
                              void* d_out, int out_size, void* d_ws, size_t ws_size,
                              hipStream_t stream) {
  (void)in_sizes; (void)n_in; (void)out_size; (void)ws_size;
  const float* fmap = (const float*)d_in[0];
  const float* Wq   = (const float*)d_in[1];
  const float* Wdw  = (const float*)d_in[2];
  const float* Wkv  = (const float*)d_in[3];
  const float* Wout = (const float*)d_in[4];
  const float* bout = (const float*)d_in[5];
  float* out = (float*)d_out;

  ushort* WqB   = (ushort*)d_ws;
  ushort* WkvB  = WqB + 512 * 256;
  ushort* WoutB = WkvB + 1024 * 256;
  ushort* fmapT = WoutB + 256 * 512;
  ushort* dwT   = fmapT + (size_t)Bx * 4096 * 256;
  ushort* kv    = dwT + (size_t)Bx * 4096 * 256;
  ushort* ctxb  = kv + (size_t)Bx * 1024 * 4096;
  float*  ctxf  = (float*)(ctxb + (size_t)Bx * 8 * 4096);
  float*  sf    = ctxf + (size_t)Bx * 8 * 64 * 64;

  convw_k<<<dim3(16, 8, 9), 256, 0, stream>>>(fmap, Wdw, fmapT, dwT,
                                              Wq, Wkv, Wout, WqB, WkvB, WoutB, ctxf);
  kvgemm3_k<<<dim3(64, Bx), 256, 0, stream>>>(WkvB, dwT, kv);
  ctx_mfma<<<dim3(8, Bx * 8), 256, 0, stream>>>(kv, ctxf, sf);
  ctx_cvt<<<dim3(Bx * 8), 256, 0, stream>>>(ctxf, sf, ctxb);
  qao_k<<<dim3(64, Bx), 256, 0, stream>>>(fmapT, WqB, ctxb, WoutB, bout, out);
}